// Round 1
// 4195.231 us; speedup vs baseline: 2.1840x; 2.1840x over previous
//
#include <hip/hip_runtime.h>
#include <hip/hip_bf16.h>
#include <cstdint>
#include <cstddef>

#define N_   64
#define T_   128
#define V_   20000
#define E_   16
#define H_   256
#define G4   1024      // 4*H
#define NT   8192      // N_*T_
#define NPAD 20096     // 157*128, W2 rows padded to tile multiple

typedef __attribute__((ext_vector_type(8))) short short8;
typedef __attribute__((ext_vector_type(4))) float f32x4;
typedef __attribute__((ext_vector_type(8))) _Float16 half8;

// packed fp16 weight blob layout (ushort offsets):
//   L1: rows 0..271  (16 e-rows from Wih1, 256 h-rows from Whh1)  -> [34][1024][8]
//   L2: rows 0..511  (256 h1-rows Wih2, 256 h2-rows Whh2)         -> [64][1024][8]
//   L3: rows 0..511  (256 h2-rows Wih3, 256 h3-rows Whh3)         -> [64][1024][8]
#define L1_OFF 0
#define L2_OFF (272 * 1024)
#define L3_OFF (784 * 1024)

__device__ __forceinline__ float sigmoidf_(float x) {
    return 1.0f / (1.0f + __expf(-x));
}

// ---------------- prep kernels ----------------

// in [R][C] row-major -> out [C][R]   (only used for W1 now)
__global__ void k_transpose(const float* __restrict__ in, float* __restrict__ out,
                            int R, int C) {
    int i = blockIdx.x * blockDim.x + threadIdx.x;
    if (i < R * C) {
        int r = i / C, c = i % C;
        out[c * R + r] = in[i];
    }
}

// Pack two torch-layout weight mats Wa [1024][Ka], Wb [1024][Kb] into
// fp16 [(Ka+Kb)/8][1024][8]: 8 consecutive k for one gate column contiguous.
__global__ void k_pack(const float* __restrict__ Wa, int Ka,
                       const float* __restrict__ Wb, int Kb,
                       unsigned short* __restrict__ dst) {
    int i = blockIdx.x * blockDim.x + threadIdx.x;
    int total = (Ka + Kb) << 10;
    if (i >= total) return;
    int k8 = i >> 13;            // / 8192
    int j  = (i >> 3) & 1023;    // gate column
    int kk = i & 7;
    int r  = (k8 << 3) + kk;     // input row
    float v = (r < Ka) ? Wa[j * Ka + r] : Wb[j * Kb + (r - Ka)];
    _Float16 hv = (_Float16)v;
    dst[i] = __builtin_bit_cast(unsigned short, hv);
}

// W2 [V_][H_] fp32 -> [NPAD][H_] bf16, zero-padded rows
__global__ void k_w2_to_bf16(const float* __restrict__ W2,
                             __hip_bfloat16* __restrict__ W2b) {
    int i = blockIdx.x * blockDim.x + threadIdx.x;
    if (i < NPAD * H_) {
        int n = i / H_;
        float v = (n < V_) ? W2[i] : 0.0f;
        W2b[i] = __float2bfloat16(v);
    }
}

// output 1: x flattened, as float
__global__ void k_write_x(const int* __restrict__ x, float* __restrict__ out) {
    int i = blockIdx.x * blockDim.x + threadIdx.x;
    if (i < NT) out[i] = (float)x[i];
}

// ---------------- LSTM phase ----------------
// dot of a uniform LDS vector (N8*8 floats) against packed fp16 weights
// w: [N8][1024][8], this thread owns gate column `tid`.
template <int N8>
__device__ __forceinline__ float dotblk(const float* __restrict__ v,
                                        const unsigned short* __restrict__ w,
                                        int tid, float acc) {
    const unsigned short* wp = w + tid * 8;
    #pragma unroll 4
    for (int b = 0; b < N8; ++b) {
        half8 wv = *(const half8*)(wp + (size_t)b * 8192);   // 16B coalesced
        const float4* hv = (const float4*)(v + b * 8);       // uniform -> broadcast
        float4 hA = hv[0], hB = hv[1];
        acc += hA.x * (float)wv[0];
        acc += hA.y * (float)wv[1];
        acc += hA.z * (float)wv[2];
        acc += hA.w * (float)wv[3];
        acc += hB.x * (float)wv[4];
        acc += hB.y * (float)wv[5];
        acc += hB.z * (float)wv[6];
        acc += hB.w * (float)wv[7];
    }
    return acc;
}

// One block per batch element. 1024 threads: thread g owns gate column g.
// Weights fp16-packed: 2.65 MB/step/CU, L2-resident (fits 4 MiB XCD L2).
__global__ __launch_bounds__(1024, 4) void k_lstm(
    const int* __restrict__ x, const float* __restrict__ h0,
    const float* __restrict__ c0, const float* __restrict__ emb,
    const unsigned short* __restrict__ Wpk,
    const float* __restrict__ bih1, const float* __restrict__ bhh1,
    const float* __restrict__ bih2, const float* __restrict__ bhh2,
    const float* __restrict__ bih3, const float* __restrict__ bhh3,
    float* __restrict__ h3_all) {
    const int n   = blockIdx.x;
    const int tid = threadIdx.x;

    const unsigned short* WL1 = Wpk + L1_OFF;
    const unsigned short* WL2 = Wpk + L2_OFF;
    const unsigned short* WL3 = Wpk + L3_OFF;

    __shared__ __align__(16) float h1[H_], c1[H_], h2[H_], c2[H_], h3[H_], c3[H_];
    __shared__ __align__(16) float e[E_];
    __shared__ float gbuf[G4];
    __shared__ int xrow[T_];

    if (tid < H_) {
        float hv = h0[n * H_ + tid], cv = c0[n * H_ + tid];
        h1[tid] = hv; c1[tid] = cv;
        h2[tid] = hv; c2[tid] = cv;
        h3[tid] = hv; c3[tid] = cv;
    }
    if (tid < T_) xrow[tid] = x[n * T_ + tid];
    const float b1s = bih1[tid] + bhh1[tid];
    const float b2s = bih2[tid] + bhh2[tid];
    const float b3s = bih3[tid] + bhh3[tid];
    __syncthreads();

    for (int t = 0; t < T_; ++t) {
        if (tid < E_) e[tid] = emb[(size_t)xrow[t] * E_ + tid];
        __syncthreads();

        // ---- layer 1: gates = e @ Wih1^T + h1 @ Whh1^T + b ----
        float acc = dotblk<2>(e, WL1, tid, b1s);               // rows 0..15
        acc = dotblk<32>(h1, WL1 + 2 * 8192, tid, acc);        // rows 16..271
        gbuf[tid] = acc;
        __syncthreads();
        if (tid < H_) {
            float gi = gbuf[tid], gf = gbuf[H_ + tid];
            float gg = gbuf[2 * H_ + tid], go = gbuf[3 * H_ + tid];
            float cn = sigmoidf_(gf) * c1[tid] + sigmoidf_(gi) * tanhf(gg);
            float hn = sigmoidf_(go) * tanhf(cn);
            c1[tid] = cn; h1[tid] = hn;
        }
        __syncthreads();

        // ---- layer 2 ----
        acc = dotblk<32>(h1, WL2, tid, b2s);
        acc = dotblk<32>(h2, WL2 + 32 * 8192, tid, acc);
        gbuf[tid] = acc;
        __syncthreads();
        if (tid < H_) {
            float gi = gbuf[tid], gf = gbuf[H_ + tid];
            float gg = gbuf[2 * H_ + tid], go = gbuf[3 * H_ + tid];
            float cn = sigmoidf_(gf) * c2[tid] + sigmoidf_(gi) * tanhf(gg);
            float hn = sigmoidf_(go) * tanhf(cn);
            c2[tid] = cn; h2[tid] = hn;
        }
        __syncthreads();

        // ---- layer 3 ----
        acc = dotblk<32>(h2, WL3, tid, b3s);
        acc = dotblk<32>(h3, WL3 + 32 * 8192, tid, acc);
        gbuf[tid] = acc;
        __syncthreads();
        if (tid < H_) {
            float gi = gbuf[tid], gf = gbuf[H_ + tid];
            float gg = gbuf[2 * H_ + tid], go = gbuf[3 * H_ + tid];
            float cn = sigmoidf_(gf) * c3[tid] + sigmoidf_(gi) * tanhf(gg);
            float hn = sigmoidf_(go) * tanhf(cn);
            c3[tid] = cn; h3[tid] = hn;
            h3_all[((size_t)n * T_ + t) * H_ + tid] = hn;
        }
        __syncthreads();
    }
}

// ---------------- head layer 1 ----------------
__global__ __launch_bounds__(256) void k_head1(
    const float* __restrict__ h3a, const float* __restrict__ W1T,
    const float* __restrict__ b1, __hip_bfloat16* __restrict__ Z) {
    const int r = blockIdx.x, j = threadIdx.x;
    __shared__ float a[H_];
    a[j] = h3a[(size_t)r * H_ + j];
    __syncthreads();
    float s = b1[j];
    #pragma unroll 8
    for (int k = 0; k < H_; ++k)
        s += a[k] * W1T[k * H_ + j];
    Z[(size_t)r * H_ + j] = __float2bfloat16(fmaxf(s, 0.0f));
}

// ---------------- head layer 2: bf16 MFMA GEMM ----------------
__global__ __launch_bounds__(256) void k_head2(
    const __hip_bfloat16* __restrict__ Zb, const __hip_bfloat16* __restrict__ W2b,
    const float* __restrict__ b2, float* __restrict__ out) {
    const int tid  = threadIdx.x;
    const int lane = tid & 63, wave = tid >> 6;
    const int wm = wave >> 1, wn = wave & 1;
    const int quad = lane >> 4, l16 = lane & 15;
    const int mbase = blockIdx.y * 128;
    const int nbase = blockIdx.x * 128;

    __shared__ short As[128 * 40];
    __shared__ short Bs[128 * 40];

    f32x4 acc[4][4] = {};

    const short* Ag = (const short*)Zb;
    const short* Bg = (const short*)W2b;

    for (int kk = 0; kk < H_; kk += 32) {
        __syncthreads();
        #pragma unroll
        for (int c = tid; c < 512; c += 256) {
            int r = c >> 2, p = (c & 3) * 8;
            *(int4*)&As[r * 40 + p] =
                *(const int4*)&Ag[(size_t)(mbase + r) * H_ + kk + p];
            *(int4*)&Bs[r * 40 + p] =
                *(const int4*)&Bg[(size_t)(nbase + r) * H_ + kk + p];
        }
        __syncthreads();

        short8 af[4], bfr[4];
        #pragma unroll
        for (int i = 0; i < 4; ++i)
            af[i] = *(const short8*)&As[(wm * 64 + i * 16 + l16) * 40 + quad * 8];
        #pragma unroll
        for (int j = 0; j < 4; ++j)
            bfr[j] = *(const short8*)&Bs[(wn * 64 + j * 16 + l16) * 40 + quad * 8];
        #pragma unroll
        for (int i = 0; i < 4; ++i)
            #pragma unroll
            for (int j = 0; j < 4; ++j)
                acc[i][j] = __builtin_amdgcn_mfma_f32_16x16x32_bf16(
                    af[i], bfr[j], acc[i][j], 0, 0, 0);
    }

    #pragma unroll
    for (int j = 0; j < 4; ++j) {
        int gc = nbase + wn * 64 + j * 16 + l16;
        if (gc >= V_) continue;
        float bias = b2[gc];
        #pragma unroll
        for (int i = 0; i < 4; ++i) {
            int rbase = mbase + wm * 64 + i * 16 + quad * 4;
            #pragma unroll
            for (int reg = 0; reg < 4; ++reg)
                out[(size_t)(rbase + reg) * V_ + gc] = acc[i][j][reg] + bias;
        }
    }
}

// ---------------- launcher ----------------
extern "C" void kernel_launch(void* const* d_in, const int* in_sizes, int n_in,
                              void* d_out, int out_size, void* d_ws, size_t ws_size,
                              hipStream_t stream) {
    const int*   x    = (const int*)  d_in[0];
    const float* h0   = (const float*)d_in[1];
    const float* c0   = (const float*)d_in[2];
    const float* emb  = (const float*)d_in[3];
    const float* Wih1 = (const float*)d_in[4];
    const float* Whh1 = (const float*)d_in[5];
    const float* bih1 = (const float*)d_in[6];
    const float* bhh1 = (const float*)d_in[7];
    const float* Wih2 = (const float*)d_in[8];
    const float* Whh2 = (const float*)d_in[9];
    const float* bih2 = (const float*)d_in[10];
    const float* bhh2 = (const float*)d_in[11];
    const float* Wih3 = (const float*)d_in[12];
    const float* Whh3 = (const float*)d_in[13];
    const float* bih3 = (const float*)d_in[14];
    const float* bhh3 = (const float*)d_in[15];
    const float* W1   = (const float*)d_in[16];
    const float* b1   = (const float*)d_in[17];
    const float* W2   = (const float*)d_in[18];
    const float* b2   = (const float*)d_in[19];
    float* out = (float*)d_out;

    // workspace layout
    unsigned short* Wpk = (unsigned short*)d_ws;          // 1296*1024 fp16
    float* W1T = (float*)(Wpk + 1296 * G4);               // 256*256 fp32
    float* h3a = W1T + H_ * H_;                           // 8192*256 fp32
    __hip_bfloat16* Zb  = (__hip_bfloat16*)(h3a + (size_t)NT * H_);  // 8192*256 bf16
    __hip_bfloat16* W2b = Zb + (size_t)NT * H_;           // 20096*256 bf16

    // prep: fp16-packed LSTM weights + W1 transpose
    {
        int n1 = 272 * G4;   // layer 1 rows
        int n2 = 512 * G4;   // layers 2,3 rows
        k_pack<<<(n1 + 255) / 256, 256, 0, stream>>>(Wih1, E_, Whh1, H_, Wpk + L1_OFF);
        k_pack<<<(n2 + 255) / 256, 256, 0, stream>>>(Wih2, H_, Whh2, H_, Wpk + L2_OFF);
        k_pack<<<(n2 + 255) / 256, 256, 0, stream>>>(Wih3, H_, Whh3, H_, Wpk + L3_OFF);
        int n = H_ * H_;
        k_transpose<<<(n + 255) / 256, 256, 0, stream>>>(W1, W1T, H_, H_);
    }
    k_w2_to_bf16<<<(NPAD * H_ + 255) / 256, 256, 0, stream>>>(W2, W2b);
    k_write_x<<<(NT + 255) / 256, 256, 0, stream>>>(x, out + (size_t)NT * V_);

    // recurrent phase: one block per batch chain
    k_lstm<<<N_, 1024, 0, stream>>>(x, h0, c0, emb, Wpk,
                                    bih1, bhh1, bih2, bhh2, bih3, bhh3, h3a);

    // head
    k_head1<<<NT, 256, 0, stream>>>(h3a, W1T, b1, Zb);
    dim3 g2(NPAD / 128, NT / 128);
    k_head2<<<g2, 256, 0, stream>>>(Zb, W2b, b2, out);
}